// Round 9
// baseline (233.001 us; speedup 1.0000x reference)
//
#include <hip/hip_runtime.h>
#include <type_traits>

typedef unsigned short u16;
typedef __attribute__((ext_vector_type(8))) short short8;   // 8 bf16 (4 VGPRs) MFMA frag
typedef __attribute__((ext_vector_type(4))) float floatx4;  // MFMA acc

#define DEV __device__ __forceinline__

DEV float bf2f(u16 u) { return __uint_as_float(((unsigned)u) << 16); }
DEV u16 f2bf(float f) {                       // RNE fp32->bf16
  unsigned u = __float_as_uint(f);
  u += 0x7fffu + ((u >> 16) & 1u);
  return (u16)(u >> 16);
}
DEV void unpack8(uint4 v, float* f) {
  f[0] = __uint_as_float(v.x << 16); f[1] = __uint_as_float(v.x & 0xffff0000u);
  f[2] = __uint_as_float(v.y << 16); f[3] = __uint_as_float(v.y & 0xffff0000u);
  f[4] = __uint_as_float(v.z << 16); f[5] = __uint_as_float(v.z & 0xffff0000u);
  f[6] = __uint_as_float(v.w << 16); f[7] = __uint_as_float(v.w & 0xffff0000u);
}
DEV void async16(const void* g, void* lds) {  // 16B global->LDS DMA (lane*16 implicit)
  __builtin_amdgcn_global_load_lds((const __attribute__((address_space(1))) void*)g,
                                   (__attribute__((address_space(3))) void*)lds, 16, 0, 0);
}
template <int N> DEV void vm_wait() {         // counted vmcnt with literal immediate
  if constexpr (N == 6)       asm volatile("s_waitcnt vmcnt(6)" ::: "memory");
  else if constexpr (N == 8)  asm volatile("s_waitcnt vmcnt(8)" ::: "memory");
  else if constexpr (N == 10) asm volatile("s_waitcnt vmcnt(10)" ::: "memory");
  else                        asm volatile("s_waitcnt vmcnt(0)" ::: "memory");
}

#define MFMA16(d, x, y) d = __builtin_amdgcn_mfma_f32_16x16x32_bf16(x, y, d, 0, 0, 0)

// ---------------- fused prep: X fp32->bf16 convert (blocks 0..4095) +
//                  weight transpose-convert + bias3 pack ----------------
__global__ __launch_bounds__(256)
void k_prep(const float* __restrict__ X, const float* __restrict__ Wq, const float* __restrict__ Wk,
            const float* __restrict__ Wv, const float* __restrict__ Wo,
            const float* __restrict__ bq, const float* __restrict__ bk, const float* __restrict__ bv,
            u16* __restrict__ Xb, u16* __restrict__ Wqkvt, u16* __restrict__ Wot,
            float* __restrict__ bias3) {
  if (blockIdx.x < 4096) {                  // ---- X convert ----
    size_t i = ((size_t)blockIdx.x * 256 + threadIdx.x) * 8;
    float4 a = *(const float4*)(X + i);
    float4 b = *(const float4*)(X + i + 4);
    union { u16 s[8]; uint4 v; } o;
    o.s[0]=f2bf(a.x); o.s[1]=f2bf(a.y); o.s[2]=f2bf(a.z); o.s[3]=f2bf(a.w);
    o.s[4]=f2bf(b.x); o.s[5]=f2bf(b.y); o.s[6]=f2bf(b.z); o.s[7]=f2bf(b.w);
    *(uint4*)(Xb + i) = o.v;
    return;
  }
  // ---- weight transpose-convert: rb = z*1024 + by*32 + bx ----
  const int rb = blockIdx.x - 4096;
  const int z = rb >> 10, bxx = rb & 31, byy = (rb >> 5) & 31;
  const float* src; u16* dst;
  switch (z) {
    case 0:  src = Wq; dst = Wqkvt;            break;
    case 1:  src = Wk; dst = Wqkvt + 1048576;  break;
    case 2:  src = Wv; dst = Wqkvt + 2097152;  break;
    default: src = Wo; dst = Wot;              break;
  }
  __shared__ float tile[32][33];
  int tx = threadIdx.x & 31, ty = threadIdx.x >> 5;  // 32 x 8
  int n0 = bxx * 32, k0 = byy * 32;
  #pragma unroll
  for (int i = 0; i < 32; i += 8) tile[ty + i][tx] = src[(size_t)(k0 + ty + i) * 1024 + n0 + tx];
  if (z == 3 && bxx == 0 && byy == 0) {
    for (int i = threadIdx.x; i < 3072; i += 256)
      bias3[i] = (i < 1024) ? bq[i] : (i < 2048 ? bk[i - 1024] : bv[i - 2048]);
  }
  __syncthreads();
  #pragma unroll
  for (int i = 0; i < 32; i += 8) dst[(size_t)(n0 + ty + i) * 1024 + k0 + tx] = f2bf(tile[tx][ty + i]);
}

// ---------------- 256x192 2-phase bf16 GEMM (QKV), BK=64 — measured-best r4 kernel ----------------
// Wave tile 128x48 (2M x 4N); 2 barriers/tile; grid 32x16 = 512 = exactly 2 rounds.
// Ledger: ph1 stages A(t+1)x4 -> buf[cur^1]; ph2 stages B(t+2)x3 -> buf[cur]; tile-end
// s_waitcnt vmcnt(3) leaves B(t+2) in flight; never vmcnt(0) in-loop; clamped tail.
template <typename OutT>
__global__ __launch_bounds__(512, 2)
void k_gemm_192(const u16* __restrict__ A, const u16* __restrict__ B,
                const float* __restrict__ bias, OutT* __restrict__ C,
                int M, int N, int K) {
  __shared__ __align__(16) u16 smA[2][2][8192];   // [buf][A rows 0-127 | 128-255][128*64]
  __shared__ __align__(16) u16 smB[2][12288];     // [buf][192 rows * 64 k]
  const int t = threadIdx.x;
  const int w = t >> 6, lane = t & 63;
  const int lr = lane & 15, q = lane >> 4, l7 = lr & 7;

  const int cpx = (int)gridDim.x >> 3;
  const int wg = ((int)blockIdx.x & 7) * cpx + ((int)blockIdx.x >> 3);
  const int nbx = N / 192;
  const int by = wg / nbx, bx = wg - by * nbx;
  const int m0 = by << 8, n0 = bx * 192;

  const int srow = t >> 3;
  const int sj8 = (((t & 7) ^ (srow & 7)) << 3);
  const size_t aoff = (size_t)(m0 + srow) * K + sj8;
  const size_t boff = (size_t)(n0 + srow) * K + sj8;
  const int dstE = w << 9;

  const int ch0 = ((q ^ l7) << 3);
  const int ch1 = (((4 | q) ^ l7) << 3);

  const int NT = K >> 6;
  const int mg = w >> 2;                     // A half (rows 0-127 / 128-255)
  const int ng = w & 3;                      // B col group (48 cols each)
  const u16* BsBase0 = &smB[0][ng * 3072];
  const u16* BsBase1 = &smB[1][ng * 3072];

  floatx4 acc[8][3];
  #pragma unroll
  for (int i = 0; i < 8; ++i)
    #pragma unroll
    for (int j = 0; j < 3; ++j)
      #pragma unroll
      for (int k = 0; k < 4; ++k) acc[i][j][k] = 0.f;

#define STGA(R, DB, KT)                                                           \
  async16(A + aoff + (size_t)((R) << 6) * K + (KT),                               \
          &smA[DB][(R) >> 1][(((R) & 1) << 12) + dstE])
#define STGB(R, DB, KT)                                                           \
  async16(B + boff + (size_t)((R) << 6) * K + (KT), &smB[DB][((R) << 12) + dstE])

  // prologue: A(0)x4 + B(0)x3 -> buf0; B(1)x3 -> buf1; wait all but newest 3
  STGA(0, 0, 0); STGA(1, 0, 0); STGA(2, 0, 0); STGA(3, 0, 0);
  STGB(0, 0, 0); STGB(1, 0, 0); STGB(2, 0, 0);
  STGB(0, 1, 64); STGB(1, 1, 64); STGB(2, 1, 64);
  asm volatile("s_waitcnt vmcnt(3)" ::: "memory");
  __builtin_amdgcn_s_barrier();

  for (int kt = 0; kt < NT; ++kt) {
    const int cur = kt & 1;
    const int kt1 = ((kt + 1 < NT) ? kt + 1 : NT - 1) << 6;   // clamp keeps ledger uniform
    const int kt2 = ((kt + 2 < NT) ? kt + 2 : NT - 1) << 6;
    const u16* As0 = &smA[cur][mg][0];
    const u16* Bs  = cur ? BsBase1 : BsBase0;

    short8 a0[4][2], a1[4][2], bf[3][2];

    // ---- ph1: read A0 + B (all 3 col-frags); stage A(t+1)x4; MFMA i=0..3
    #pragma unroll
    for (int i = 0; i < 4; ++i) {
      a0[i][0] = *(const short8*)&As0[(((i << 4) + lr) << 6) + ch0];
      a0[i][1] = *(const short8*)&As0[(((i << 4) + lr) << 6) + ch1];
    }
    #pragma unroll
    for (int j = 0; j < 3; ++j) {
      bf[j][0] = *(const short8*)&Bs[(((j << 4) + lr) << 6) + ch0];
      bf[j][1] = *(const short8*)&Bs[(((j << 4) + lr) << 6) + ch1];
    }
    if (cur) { STGA(0, 0, kt1); STGA(1, 0, kt1); STGA(2, 0, kt1); STGA(3, 0, kt1); }
    else     { STGA(0, 1, kt1); STGA(1, 1, kt1); STGA(2, 1, kt1); STGA(3, 1, kt1); }
    __builtin_amdgcn_s_setprio(1);
    #pragma unroll
    for (int i = 0; i < 4; ++i)
      #pragma unroll
      for (int j = 0; j < 3; ++j) {
        MFMA16(acc[i][j], a0[i][0], bf[j][0]);
        MFMA16(acc[i][j], a0[i][1], bf[j][1]);
      }
    __builtin_amdgcn_s_setprio(0);
    __builtin_amdgcn_s_barrier();

    // ---- ph2: read A1; stage B(t+2)x3 -> buf[cur]; MFMA i=4..7
    #pragma unroll
    for (int i = 0; i < 4; ++i) {
      a1[i][0] = *(const short8*)&As0[((64 + (i << 4) + lr) << 6) + ch0];
      a1[i][1] = *(const short8*)&As0[((64 + (i << 4) + lr) << 6) + ch1];
    }
    if (cur) { STGB(0, 1, kt2); STGB(1, 1, kt2); STGB(2, 1, kt2); }
    else     { STGB(0, 0, kt2); STGB(1, 0, kt2); STGB(2, 0, kt2); }
    __builtin_amdgcn_s_setprio(1);
    #pragma unroll
    for (int i = 0; i < 4; ++i)
      #pragma unroll
      for (int j = 0; j < 3; ++j) {
        MFMA16(acc[i + 4][j], a1[i][0], bf[j][0]);
        MFMA16(acc[i + 4][j], a1[i][1], bf[j][1]);
      }
    __builtin_amdgcn_s_setprio(0);
    asm volatile("s_waitcnt vmcnt(3)" ::: "memory");   // A(t+1)+B(t+1) landed; B(t+2) in flight
    __builtin_amdgcn_s_barrier();
  }
#undef STGA
#undef STGB

  asm volatile("s_waitcnt vmcnt(0)" ::: "memory");     // drain clamped tail stages

  const int wrm = m0 + (mg << 7);
  const int wcn = n0 + ng * 48;
  const int lq = q << 2;
  #pragma unroll
  for (int j = 0; j < 3; ++j) {
    const int cn = wcn + (j << 4) + lr;
    const float bv = bias[cn];
    #pragma unroll
    for (int i = 0; i < 8; ++i) {
      const int rm = wrm + (i << 4) + lq;
      #pragma unroll
      for (int rr = 0; rr < 4; ++rr) {
        float v = acc[i][j][rr] + bv;
        if constexpr (std::is_same<OutT, u16>::value) C[(size_t)(rm + rr) * N + cn] = f2bf(v);
        else                                          C[(size_t)(rm + rr) * N + cn] = v;
      }
    }
  }
}

// ---------------- 128xBN multi-block/CU async bf16 GEMM (out-projection), BK=64 ----------------
// r9: BN=64 -> LDS 48 KiB -> 3 blocks/CU (was BN=128, 64 KiB, 2/CU); grid 64x16 = 1024.
// 12 resident waves/CU (3/SIMD) for latency backfill. Ledger: ph2 stages tile t+2
// (A x4 + B xNBW) into buf[cur]; tile-end vmcnt(4+NBW) leaves t+2 in flight (never 0).
template <int BN, typename OutT>
__global__ __launch_bounds__(256, 2)
void k_gemm_a(const u16* __restrict__ A, const u16* __restrict__ B,
              const float* __restrict__ bias, OutT* __restrict__ C,
              int M, int N, int K) {
  constexpr int NBW = BN / 32;
  __shared__ __align__(16) u16 smA[2][8192];
  __shared__ __align__(16) u16 smB[2][BN * 64];
  const int t = threadIdx.x;
  const int w = t >> 6, lane = t & 63;
  const int lr = lane & 15, q = lane >> 4, l7 = lr & 7;

  const int cpx = (int)gridDim.x >> 3;
  const int wg = ((int)blockIdx.x & 7) * cpx + ((int)blockIdx.x >> 3);
  const int nbx = N / BN;
  const int by = wg / nbx, bx = wg - by * nbx;
  const int m0 = by << 7, n0 = bx * BN;

  const int srow = t >> 3;
  const int sj8 = (((t & 7) ^ (srow & 7)) << 3);
  const size_t aoff = (size_t)(m0 + srow) * K + sj8;
  const size_t boff = (size_t)(n0 + srow) * K + sj8;
  const int dstE = w << 9;

  const int ch0 = ((q ^ l7) << 3);
  const int ch1 = (((4 | q) ^ l7) << 3);

  const int mg = w >> 1, ng = w & 1;
  const int NT = K >> 6;

  floatx4 acc[4][NBW];
  #pragma unroll
  for (int i = 0; i < 4; ++i)
    #pragma unroll
    for (int j = 0; j < NBW; ++j)
      #pragma unroll
      for (int k = 0; k < 4; ++k) acc[i][j][k] = 0.f;

#define STGA(R, DB, KT) async16(A + aoff + (size_t)((R) << 5) * K + (KT), &smA[DB][((R) << 11) + dstE])
#define STGB(R, DB, KT) async16(B + boff + (size_t)((R) << 5) * K + (KT), &smB[DB][((R) << 11) + dstE])

  #pragma unroll
  for (int r = 0; r < 4; ++r) STGA(r, 0, 0);
  #pragma unroll
  for (int r = 0; r < NBW; ++r) STGB(r, 0, 0);
  #pragma unroll
  for (int r = 0; r < 4; ++r) STGA(r, 1, 64);
  #pragma unroll
  for (int r = 0; r < NBW; ++r) STGB(r, 1, 64);
  vm_wait<4 + NBW>();
  __builtin_amdgcn_s_barrier();
  __builtin_amdgcn_sched_barrier(0);

  for (int kt = 0; kt < NT; ++kt) {
    const int cur = kt & 1;
    const int kt2 = ((kt + 2 < NT) ? kt + 2 : NT - 1) << 6;
    const u16* As0 = &smA[cur][0];
    const u16* Bs0 = &smB[cur][0];
    short8 a[4][2], b[NBW][2];

    #pragma unroll
    for (int i = 0; i < 4; ++i) a[i][0] = *(const short8*)&As0[(((mg << 6) + (i << 4) + lr) << 6) + ch0];
    #pragma unroll
    for (int j = 0; j < NBW; ++j) b[j][0] = *(const short8*)&Bs0[((ng * (BN / 2) + (j << 4) + lr) << 6) + ch0];
    #pragma unroll
    for (int i = 0; i < 4; ++i) a[i][1] = *(const short8*)&As0[(((mg << 6) + (i << 4) + lr) << 6) + ch1];
    #pragma unroll
    for (int j = 0; j < NBW; ++j) b[j][1] = *(const short8*)&Bs0[((ng * (BN / 2) + (j << 4) + lr) << 6) + ch1];
    __builtin_amdgcn_s_setprio(1);
    #pragma unroll
    for (int i = 0; i < 4; ++i)
      #pragma unroll
      for (int j = 0; j < NBW; ++j) MFMA16(acc[i][j], a[i][0], b[j][0]);
    __builtin_amdgcn_s_setprio(0);
    asm volatile("s_waitcnt lgkmcnt(0)" ::: "memory");
    __builtin_amdgcn_s_barrier();
    __builtin_amdgcn_sched_barrier(0);

    #pragma unroll
    for (int r = 0; r < 4; ++r) STGA(r, cur, kt2);
    #pragma unroll
    for (int r = 0; r < NBW; ++r) STGB(r, cur, kt2);
    __builtin_amdgcn_sched_barrier(0);
    __builtin_amdgcn_s_setprio(1);
    #pragma unroll
    for (int i = 0; i < 4; ++i)
      #pragma unroll
      for (int j = 0; j < NBW; ++j) MFMA16(acc[i][j], a[i][1], b[j][1]);
    __builtin_amdgcn_s_setprio(0);
    vm_wait<4 + NBW>();
    __builtin_amdgcn_s_barrier();
    __builtin_amdgcn_sched_barrier(0);
  }
#undef STGA
#undef STGB

  asm volatile("s_waitcnt vmcnt(0)" ::: "memory");

  const int wrm = m0 + (mg << 6);
  const int wcn = n0 + ng * (BN / 2);
  const int lq = q << 2;
  #pragma unroll
  for (int j = 0; j < NBW; ++j) {
    const int cn = wcn + (j << 4) + lr;
    const float bv = bias[cn];
    #pragma unroll
    for (int i = 0; i < 4; ++i) {
      const int rm = wrm + (i << 4) + lq;
      #pragma unroll
      for (int rr = 0; rr < 4; ++rr) {
        float v = acc[i][j][rr] + bv;
        if constexpr (std::is_same<OutT, u16>::value) C[(size_t)(rm + rr) * N + cn] = f2bf(v);
        else                                          C[(size_t)(rm + rr) * N + cn] = v;
      }
    }
  }
}

// ---------------- Gram partials via MFMA + qsum partials (r7, verified) ----------------
__global__ __launch_bounds__(256)
void k_gpart2(const u16* __restrict__ QKV, float* __restrict__ Gpart, float* __restrict__ qpart) {
  const int chunk = blockIdx.x;            // 0..15 (128 a each)
  const int nh = blockIdx.y;               // 0..63
  const int n = nh >> 4, h = nh & 15;
  const int t = threadIdx.x, w = t >> 6, lane = t & 63;
  const int lr = lane & 15, lko = (lane >> 4) << 3;

  __shared__ __align__(16) u16 Qt[64 * 136];   // x-major, a-stride 136 (17.4 KB)
  __shared__ float red[256];

  // transpose-in: thread t -> (a_local = t>>1, x-half = t&1); 4x uint4 = 64B
  const int a_local = t >> 1, xh = t & 1;
  const int a = chunk * 128 + a_local;
  const uint4* qp = (const uint4*)(QKV + (size_t)(n * 2048 + h * 128 + (a >> 4)) * 3072
                                   + ((a & 15) << 6) + (xh << 5));
  union { u16 s[8]; uint4 v; } qv[4];
  #pragma unroll
  for (int j = 0; j < 4; ++j) qv[j].v = qp[j];
  #pragma unroll
  for (int j = 0; j < 4; ++j)
    #pragma unroll
    for (int e = 0; e < 8; ++e)
      Qt[((xh << 5) + j * 8 + e) * 136 + a_local] = qv[j].s[e];   // <=2-way bank alias (free)
  __syncthreads();

  // qsum partial: thread (x = t&63, c = t>>6) sums Qt[x][c*32 .. +31]
  {
    const int x = t & 63, c = t >> 6;
    const u16* base = &Qt[x * 136 + (c << 5)];
    float s = 0.f;
    #pragma unroll
    for (int k = 0; k < 4; ++k) {
      float f[8]; unpack8(*(const uint4*)(base + k * 8), f);
      #pragma unroll
      for (int e = 0; e < 8; ++e) s += f[e];
    }
    red[t] = s;
  }
  __syncthreads();
  if (t < 64)
    qpart[((size_t)nh * 16 + chunk) * 64 + t] = red[t] + red[t + 64] + red[t + 128] + red[t + 192];

  // Gram: K-loop over 128 a in 4 steps of 32; wave w owns C row-block i=w
  floatx4 acc[4];
  #pragma unroll
  for (int j = 0; j < 4; ++j)
    #pragma unroll
    for (int k = 0; k < 4; ++k) acc[j][k] = 0.f;
  #pragma unroll
  for (int ks = 0; ks < 4; ++ks) {
    short8 f[4];
    #pragma unroll
    for (int i = 0; i < 4; ++i) f[i] = *(const short8*)&Qt[((i << 4) + lr) * 136 + (ks << 5) + lko];
    #pragma unroll
    for (int j = 0; j < 4; ++j)
      acc[j] = __builtin_amdgcn_mfma_f32_16x16x32_bf16(f[w], f[j], acc[j], 0, 0, 0);
  }
  float* o = Gpart + ((size_t)nh * 16 + chunk) * 4096;
  const int quad = lane >> 4;
  #pragma unroll
  for (int j = 0; j < 4; ++j)
    #pragma unroll
    for (int r = 0; r < 4; ++r)
      o[((w << 4) + (quad << 2) + r) * 64 + (j << 4) + lr] = acc[j][r];
}

// ---------------- Gpart/qpart reduce -> bf16 G + fp32 qs ----------------
__global__ __launch_bounds__(256)
void k_gred(const float* __restrict__ Gpart, const float* __restrict__ qpart,
            u16* __restrict__ G, float* __restrict__ qs_g) {
  const int nh = blockIdx.y;               // 0..63
  const int t = threadIdx.x;
  const int e0 = (blockIdx.x << 9) + (t << 1);   // 2 elems/thread, 512/block
  const float2* gp = (const float2*)(Gpart + (size_t)nh * 65536 + e0);
  float sx = 0.f, sy = 0.f;
  #pragma unroll
  for (int c = 0; c < 16; ++c) { float2 v = gp[c * 2048]; sx += v.x; sy += v.y; }
  *(unsigned*)(G + (size_t)nh * 4096 + e0) = (unsigned)f2bf(sx) | ((unsigned)f2bf(sy) << 16);
  if (blockIdx.x == 0 && t < 64) {
    float s = 0.f;
    #pragma unroll
    for (int rc = 0; rc < 16; ++rc) s += qpart[((size_t)nh * 16 + rc) * 64 + t];
    qs_g[nh * 64 + t] = s;
  }
}

// ---------------- fused: load G -> U = K*G (MFMA, LDS) -> Taylor denom/diag -> mid = diag*V ----
// r8 form (verified): grid 16x64 (4 blocks/CU), 128 a-rows/block, LDS 26.7 KB.
__global__ __launch_bounds__(256)
void k_kgd(const u16* __restrict__ QKV, const u16* __restrict__ G,
           const float* __restrict__ qs_g, u16* __restrict__ mid) {
  const int chunk = blockIdx.x;            // 0..15 (128 a each)
  const int nh = blockIdx.y;               // 0..63
  const int n = nh >> 4, h = nh & 15;
  const int t = threadIdx.x, w = t >> 6, lane = t & 63;
  const int lr = lane & 15, lko = (lane >> 4) << 3;

  __shared__ __align__(16) u16 Gs[4096];      // bf16 G_h, 64x64 (8 KB)
  __shared__ __align__(16) u16 Us[128 * 72];  // bf16 U rows, padded stride 72 (18.4 KB)
  __shared__ float qs[64];

  // --- stage 0: coalesced copy of pre-reduced G (8 KB) + qs ---
  const uint4* gsrc = (const uint4*)(G + (size_t)nh * 4096);
  ((uint4*)Gs)[t] = gsrc[t];
  ((uint4*)Gs)[256 + t] = gsrc[256 + t];
  if (t < 64) qs[t] = qs_g[nh * 64 + t];
  __syncthreads();

  // --- stage 1: U = K * G via MFMA (each wave: 32 a-rows x 64 cols) ---
  short8 af[2][2], bfr[4][2];
  #pragma unroll
  for (int i = 0; i < 2; ++i) {
    const int arow = chunk * 8 + (w << 1) + i;          // (a>>4) within head
    const u16* kp = QKV + (size_t)(n * 2048 + h * 128 + arow) * 3072 + 1024 + lr * 64;
    #pragma unroll
    for (int s = 0; s < 2; ++s) af[i][s] = *(const short8*)(kp + s * 32 + lko);
  }
  #pragma unroll
  for (int j = 0; j < 4; ++j)
    #pragma unroll
    for (int s = 0; s < 2; ++s)
      bfr[j][s] = *(const short8*)&Gs[((j << 4) + lr) * 64 + s * 32 + lko];
  floatx4 acc[2][4];
  #pragma unroll
  for (int i = 0; i < 2; ++i)
    #pragma unroll
    for (int j = 0; j < 4; ++j)
      #pragma unroll
      for (int k = 0; k < 4; ++k) acc[i][j][k] = 0.f;
  #pragma unroll
  for (int s = 0; s < 2; ++s)
    #pragma unroll
    for (int i = 0; i < 2; ++i)
      #pragma unroll
      for (int j = 0; j < 4; ++j)
        acc[i][j] = __builtin_amdgcn_mfma_f32_16x16x32_bf16(af[i][s], bfr[j][s], acc[i][j], 0, 0, 0);
  const int rq = (lane >> 4) << 2;
  #pragma unroll
  for (int i = 0; i < 2; ++i)
    #pragma unroll
    for (int j = 0; j < 4; ++j)
      #pragma unroll
      for (int r = 0; r < 4; ++r) {
        int a_local = (w << 5) + (i << 4) + rq + r;     // 0..127
        Us[a_local * 72 + (j << 4) + lr] = f2bf(acc[i][j][r]);
      }
  __syncthreads();

  // --- stage 2: 2 threads per a (32 x's each): Taylor denom + diag; mid = diag * V ---
  const int al = t >> 1, xh = t & 1;
  const int b = chunk * 128 + al;          // a within head
  const int R = n * 2048 + h * 128 + (b >> 4);
  const u16* row = QKV + (size_t)R * 3072 + ((b & 15) << 6) + (xh << 5);
  const uint4* qp = (const uint4*)row;
  const uint4* kp = (const uint4*)(row + 1024);
  const uint4* vp = (const uint4*)(row + 2048);
  const uint4* up = (const uint4*)&Us[al * 72 + (xh << 5)];
  float sbb = 0.f, s1 = 0.f, quad = 0.f;
  #pragma unroll
  for (int xo = 0; xo < 4; ++xo) {
    float kx[8], qx[8], ux[8];
    unpack8(kp[xo], kx); unpack8(qp[xo], qx); unpack8(up[xo], ux);
    #pragma unroll
    for (int xi = 0; xi < 8; ++xi) {
      sbb  += qx[xi] * kx[xi];
      quad += ux[xi] * kx[xi];
      s1   += qs[(xh << 5) + xo * 8 + xi] * kx[xi];
    }
  }
  sbb  += __shfl_xor(sbb, 1);              // pair-combine (lanes 2k <-> 2k+1)
  quad += __shfl_xor(quad, 1);
  s1   += __shfl_xor(s1, 1);
  const float c1 = 0.0009765625f;  // 1/1024
  float denom = 2048.f + s1 * c1 + 0.5f * quad * c1 * c1;
  float d = expf(sbb * c1) / denom;
  u16* mp = mid + (size_t)R * 1024 + ((b & 15) << 6) + (xh << 5);
  #pragma unroll
  for (int xo = 0; xo < 4; ++xo) {
    float f[8]; unpack8(vp[xo], f);
    union { u16 s[8]; uint4 v; } o;
    #pragma unroll
    for (int k = 0; k < 8; ++k) o.s[k] = f2bf(f[k] * d);
    *(uint4*)(mp + xo * 8) = o.v;
  }
}

// ---------------- launch ----------------
extern "C" void kernel_launch(void* const* d_in, const int* in_sizes, int n_in,
                              void* d_out, int out_size, void* d_ws, size_t ws_size,
                              hipStream_t stream) {
  (void)in_sizes; (void)n_in; (void)out_size; (void)ws_size;
  const float* X  = (const float*)d_in[0];
  const float* Wq = (const float*)d_in[1];
  const float* bq = (const float*)d_in[2];
  const float* Wk = (const float*)d_in[3];
  const float* bk = (const float*)d_in[4];
  const float* Wv = (const float*)d_in[5];
  const float* bv = (const float*)d_in[6];
  const float* Wo = (const float*)d_in[7];
  const float* bo = (const float*)d_in[8];
  float* out = (float*)d_out;
  char* ws = (char*)d_ws;

  // ws+0 (16 MB) triple use, strictly stream-ordered:
  //   Xb (prep->QKV GEMM)  ->  Gpart fp32 64x16x4096 (gpart2->gred)  ->  mid (kgd->outproj)
  u16*   Xb    = (u16*)(ws + 0);
  float* Gpart = (float*)(ws + 0);
  u16*   mid   = (u16*)(ws + 0);
  u16*   Wqkvt = (u16*)(ws + 16777216);          //  6 MB (dead after QKV GEMM)
  u16*   Gred  = (u16*)(ws + 16777216);          // 512 KB, overlays dead Wqkvt
  float* qsg   = (float*)(ws + 17301504);        //  16 KB, overlays dead Wqkvt
  u16*   Wot   = (u16*)(ws + 23068672);          //  2 MB
  float* bias3 = (float*)(ws + 25165824);        // 12 KB
  u16*   QKV   = (u16*)(ws + 25182208);          // 48 MB (8192 x [Q|K|V])
  float* qpart = (float*)(ws + 75513856);        // 256 KB

  k_prep<<<8192, 256, 0, stream>>>(X, Wq, Wk, Wv, Wo, bq, bk, bv, Xb, Wqkvt, Wot, bias3);
  // QKV GEMM: measured-best r4 kernel, grid 512 = exactly 2 rounds
  k_gemm_192<u16><<<512, 512, 0, stream>>>(Xb, Wqkvt, bias3, QKV, 8192, 3072, 1024);
  // Gram partials: 16 chunks x 64 nh = 1024 blocks (4/CU)
  k_gpart2<<<dim3(16, 64), 256, 0, stream>>>(QKV, Gpart, qpart);
  k_gred<<<dim3(8, 64), 256, 0, stream>>>(Gpart, qpart, Gred, qsg);
  // kgd: 16 chunks x 64 nh = 1024 blocks (4/CU)
  k_kgd<<<dim3(16, 64), 256, 0, stream>>>(QKV, Gred, qsg, mid);
  // out-projection: 128x64 tiles, 3 blocks/CU -> grid (8192/128)*(1024/64) = 1024
  k_gemm_a<64, float><<<1024, 256, 0, stream>>>(mid, Wot, bo, out, 8192, 1024, 1024);
}

// Round 11
// 227.244 us; speedup vs baseline: 1.0253x; 1.0253x over previous
//
#include <hip/hip_runtime.h>
#include <type_traits>

typedef unsigned short u16;
typedef __attribute__((ext_vector_type(8))) short short8;   // 8 bf16 (4 VGPRs) MFMA frag
typedef __attribute__((ext_vector_type(4))) float floatx4;  // MFMA acc

#define DEV __device__ __forceinline__

DEV float bf2f(u16 u) { return __uint_as_float(((unsigned)u) << 16); }
DEV u16 f2bf(float f) {                       // RNE fp32->bf16
  unsigned u = __float_as_uint(f);
  u += 0x7fffu + ((u >> 16) & 1u);
  return (u16)(u >> 16);
}
DEV void unpack8(uint4 v, float* f) {
  f[0] = __uint_as_float(v.x << 16); f[1] = __uint_as_float(v.x & 0xffff0000u);
  f[2] = __uint_as_float(v.y << 16); f[3] = __uint_as_float(v.y & 0xffff0000u);
  f[4] = __uint_as_float(v.z << 16); f[5] = __uint_as_float(v.z & 0xffff0000u);
  f[6] = __uint_as_float(v.w << 16); f[7] = __uint_as_float(v.w & 0xffff0000u);
}
DEV void async16(const void* g, void* lds) {  // 16B global->LDS DMA (lane*16 implicit)
  __builtin_amdgcn_global_load_lds((const __attribute__((address_space(1))) void*)g,
                                   (__attribute__((address_space(3))) void*)lds, 16, 0, 0);
}
template <int N> DEV void vm_wait() {         // counted vmcnt with literal immediate
  if constexpr (N == 6)       asm volatile("s_waitcnt vmcnt(6)" ::: "memory");
  else if constexpr (N == 8)  asm volatile("s_waitcnt vmcnt(8)" ::: "memory");
  else if constexpr (N == 10) asm volatile("s_waitcnt vmcnt(10)" ::: "memory");
  else                        asm volatile("s_waitcnt vmcnt(0)" ::: "memory");
}

#define MFMA16(d, x, y) d = __builtin_amdgcn_mfma_f32_16x16x32_bf16(x, y, d, 0, 0, 0)

// ---------------- fused prep: X fp32->bf16 convert (blocks 0..4095) +
//                  weight transpose-convert + bias3 pack ----------------
__global__ __launch_bounds__(256)
void k_prep(const float* __restrict__ X, const float* __restrict__ Wq, const float* __restrict__ Wk,
            const float* __restrict__ Wv, const float* __restrict__ Wo,
            const float* __restrict__ bq, const float* __restrict__ bk, const float* __restrict__ bv,
            u16* __restrict__ Xb, u16* __restrict__ Wqkvt, u16* __restrict__ Wot,
            float* __restrict__ bias3) {
  if (blockIdx.x < 4096) {                  // ---- X convert ----
    size_t i = ((size_t)blockIdx.x * 256 + threadIdx.x) * 8;
    float4 a = *(const float4*)(X + i);
    float4 b = *(const float4*)(X + i + 4);
    union { u16 s[8]; uint4 v; } o;
    o.s[0]=f2bf(a.x); o.s[1]=f2bf(a.y); o.s[2]=f2bf(a.z); o.s[3]=f2bf(a.w);
    o.s[4]=f2bf(b.x); o.s[5]=f2bf(b.y); o.s[6]=f2bf(b.z); o.s[7]=f2bf(b.w);
    *(uint4*)(Xb + i) = o.v;
    return;
  }
  // ---- weight transpose-convert: rb = z*1024 + by*32 + bx ----
  const int rb = blockIdx.x - 4096;
  const int z = rb >> 10, bxx = rb & 31, byy = (rb >> 5) & 31;
  const float* src; u16* dst;
  switch (z) {
    case 0:  src = Wq; dst = Wqkvt;            break;
    case 1:  src = Wk; dst = Wqkvt + 1048576;  break;
    case 2:  src = Wv; dst = Wqkvt + 2097152;  break;
    default: src = Wo; dst = Wot;              break;
  }
  __shared__ float tile[32][33];
  int tx = threadIdx.x & 31, ty = threadIdx.x >> 5;  // 32 x 8
  int n0 = bxx * 32, k0 = byy * 32;
  #pragma unroll
  for (int i = 0; i < 32; i += 8) tile[ty + i][tx] = src[(size_t)(k0 + ty + i) * 1024 + n0 + tx];
  if (z == 3 && bxx == 0 && byy == 0) {
    for (int i = threadIdx.x; i < 3072; i += 256)
      bias3[i] = (i < 1024) ? bq[i] : (i < 2048 ? bk[i - 1024] : bv[i - 2048]);
  }
  __syncthreads();
  #pragma unroll
  for (int i = 0; i < 32; i += 8) dst[(size_t)(n0 + ty + i) * 1024 + k0 + tx] = f2bf(tile[tx][ty + i]);
}

// ---------------- 256x192 2-phase bf16 GEMM (QKV), BK=64 — measured-best r4 kernel ----------------
// FROZEN: eight schedule/geometry variants landed in the 61-71 us band; this is the best.
template <typename OutT>
__global__ __launch_bounds__(512, 2)
void k_gemm_192(const u16* __restrict__ A, const u16* __restrict__ B,
                const float* __restrict__ bias, OutT* __restrict__ C,
                int M, int N, int K) {
  __shared__ __align__(16) u16 smA[2][2][8192];   // [buf][A rows 0-127 | 128-255][128*64]
  __shared__ __align__(16) u16 smB[2][12288];     // [buf][192 rows * 64 k]
  const int t = threadIdx.x;
  const int w = t >> 6, lane = t & 63;
  const int lr = lane & 15, q = lane >> 4, l7 = lr & 7;

  const int cpx = (int)gridDim.x >> 3;
  const int wg = ((int)blockIdx.x & 7) * cpx + ((int)blockIdx.x >> 3);
  const int nbx = N / 192;
  const int by = wg / nbx, bx = wg - by * nbx;
  const int m0 = by << 8, n0 = bx * 192;

  const int srow = t >> 3;
  const int sj8 = (((t & 7) ^ (srow & 7)) << 3);
  const size_t aoff = (size_t)(m0 + srow) * K + sj8;
  const size_t boff = (size_t)(n0 + srow) * K + sj8;
  const int dstE = w << 9;

  const int ch0 = ((q ^ l7) << 3);
  const int ch1 = (((4 | q) ^ l7) << 3);

  const int NT = K >> 6;
  const int mg = w >> 2;                     // A half (rows 0-127 / 128-255)
  const int ng = w & 3;                      // B col group (48 cols each)
  const u16* BsBase0 = &smB[0][ng * 3072];
  const u16* BsBase1 = &smB[1][ng * 3072];

  floatx4 acc[8][3];
  #pragma unroll
  for (int i = 0; i < 8; ++i)
    #pragma unroll
    for (int j = 0; j < 3; ++j)
      #pragma unroll
      for (int k = 0; k < 4; ++k) acc[i][j][k] = 0.f;

#define STGA(R, DB, KT)                                                           \
  async16(A + aoff + (size_t)((R) << 6) * K + (KT),                               \
          &smA[DB][(R) >> 1][(((R) & 1) << 12) + dstE])
#define STGB(R, DB, KT)                                                           \
  async16(B + boff + (size_t)((R) << 6) * K + (KT), &smB[DB][((R) << 12) + dstE])

  // prologue: A(0)x4 + B(0)x3 -> buf0; B(1)x3 -> buf1; wait all but newest 3
  STGA(0, 0, 0); STGA(1, 0, 0); STGA(2, 0, 0); STGA(3, 0, 0);
  STGB(0, 0, 0); STGB(1, 0, 0); STGB(2, 0, 0);
  STGB(0, 1, 64); STGB(1, 1, 64); STGB(2, 1, 64);
  asm volatile("s_waitcnt vmcnt(3)" ::: "memory");
  __builtin_amdgcn_s_barrier();

  for (int kt = 0; kt < NT; ++kt) {
    const int cur = kt & 1;
    const int kt1 = ((kt + 1 < NT) ? kt + 1 : NT - 1) << 6;   // clamp keeps ledger uniform
    const int kt2 = ((kt + 2 < NT) ? kt + 2 : NT - 1) << 6;
    const u16* As0 = &smA[cur][mg][0];
    const u16* Bs  = cur ? BsBase1 : BsBase0;

    short8 a0[4][2], a1[4][2], bf[3][2];

    // ---- ph1: read A0 + B (all 3 col-frags); stage A(t+1)x4; MFMA i=0..3
    #pragma unroll
    for (int i = 0; i < 4; ++i) {
      a0[i][0] = *(const short8*)&As0[(((i << 4) + lr) << 6) + ch0];
      a0[i][1] = *(const short8*)&As0[(((i << 4) + lr) << 6) + ch1];
    }
    #pragma unroll
    for (int j = 0; j < 3; ++j) {
      bf[j][0] = *(const short8*)&Bs[(((j << 4) + lr) << 6) + ch0];
      bf[j][1] = *(const short8*)&Bs[(((j << 4) + lr) << 6) + ch1];
    }
    if (cur) { STGA(0, 0, kt1); STGA(1, 0, kt1); STGA(2, 0, kt1); STGA(3, 0, kt1); }
    else     { STGA(0, 1, kt1); STGA(1, 1, kt1); STGA(2, 1, kt1); STGA(3, 1, kt1); }
    __builtin_amdgcn_s_setprio(1);
    #pragma unroll
    for (int i = 0; i < 4; ++i)
      #pragma unroll
      for (int j = 0; j < 3; ++j) {
        MFMA16(acc[i][j], a0[i][0], bf[j][0]);
        MFMA16(acc[i][j], a0[i][1], bf[j][1]);
      }
    __builtin_amdgcn_s_setprio(0);
    __builtin_amdgcn_s_barrier();

    // ---- ph2: read A1; stage B(t+2)x3 -> buf[cur]; MFMA i=4..7
    #pragma unroll
    for (int i = 0; i < 4; ++i) {
      a1[i][0] = *(const short8*)&As0[((64 + (i << 4) + lr) << 6) + ch0];
      a1[i][1] = *(const short8*)&As0[((64 + (i << 4) + lr) << 6) + ch1];
    }
    if (cur) { STGB(0, 1, kt2); STGB(1, 1, kt2); STGB(2, 1, kt2); }
    else     { STGB(0, 0, kt2); STGB(1, 0, kt2); STGB(2, 0, kt2); }
    __builtin_amdgcn_s_setprio(1);
    #pragma unroll
    for (int i = 0; i < 4; ++i)
      #pragma unroll
      for (int j = 0; j < 3; ++j) {
        MFMA16(acc[i + 4][j], a1[i][0], bf[j][0]);
        MFMA16(acc[i + 4][j], a1[i][1], bf[j][1]);
      }
    __builtin_amdgcn_s_setprio(0);
    asm volatile("s_waitcnt vmcnt(3)" ::: "memory");   // A(t+1)+B(t+1) landed; B(t+2) in flight
    __builtin_amdgcn_s_barrier();
  }
#undef STGA
#undef STGB

  asm volatile("s_waitcnt vmcnt(0)" ::: "memory");     // drain clamped tail stages

  const int wrm = m0 + (mg << 7);
  const int wcn = n0 + ng * 48;
  const int lq = q << 2;
  #pragma unroll
  for (int j = 0; j < 3; ++j) {
    const int cn = wcn + (j << 4) + lr;
    const float bv = bias[cn];
    #pragma unroll
    for (int i = 0; i < 8; ++i) {
      const int rm = wrm + (i << 4) + lq;
      #pragma unroll
      for (int rr = 0; rr < 4; ++rr) {
        float v = acc[i][j][rr] + bv;
        if constexpr (std::is_same<OutT, u16>::value) C[(size_t)(rm + rr) * N + cn] = f2bf(v);
        else                                          C[(size_t)(rm + rr) * N + cn] = v;
      }
    }
  }
}

// ---------------- 128xBN 2-blocks/CU async bf16 GEMM (out-projection), BK=64 ----------------
// r8-best config (BN=128, grid 512). r9's BN=64 experiment was neutral-negative; reverted.
template <int BN, typename OutT>
__global__ __launch_bounds__(256, 2)
void k_gemm_a(const u16* __restrict__ A, const u16* __restrict__ B,
              const float* __restrict__ bias, OutT* __restrict__ C,
              int M, int N, int K) {
  constexpr int NBW = BN / 32;
  __shared__ __align__(16) u16 smA[2][8192];
  __shared__ __align__(16) u16 smB[2][BN * 64];
  const int t = threadIdx.x;
  const int w = t >> 6, lane = t & 63;
  const int lr = lane & 15, q = lane >> 4, l7 = lr & 7;

  const int cpx = (int)gridDim.x >> 3;
  const int wg = ((int)blockIdx.x & 7) * cpx + ((int)blockIdx.x >> 3);
  const int nbx = N / BN;
  const int by = wg / nbx, bx = wg - by * nbx;
  const int m0 = by << 7, n0 = bx * BN;

  const int srow = t >> 3;
  const int sj8 = (((t & 7) ^ (srow & 7)) << 3);
  const size_t aoff = (size_t)(m0 + srow) * K + sj8;
  const size_t boff = (size_t)(n0 + srow) * K + sj8;
  const int dstE = w << 9;

  const int ch0 = ((q ^ l7) << 3);
  const int ch1 = (((4 | q) ^ l7) << 3);

  const int mg = w >> 1, ng = w & 1;
  const int NT = K >> 6;

  floatx4 acc[4][NBW];
  #pragma unroll
  for (int i = 0; i < 4; ++i)
    #pragma unroll
    for (int j = 0; j < NBW; ++j)
      #pragma unroll
      for (int k = 0; k < 4; ++k) acc[i][j][k] = 0.f;

#define STGA(R, DB, KT) async16(A + aoff + (size_t)((R) << 5) * K + (KT), &smA[DB][((R) << 11) + dstE])
#define STGB(R, DB, KT) async16(B + boff + (size_t)((R) << 5) * K + (KT), &smB[DB][((R) << 11) + dstE])

  #pragma unroll
  for (int r = 0; r < 4; ++r) STGA(r, 0, 0);
  #pragma unroll
  for (int r = 0; r < NBW; ++r) STGB(r, 0, 0);
  #pragma unroll
  for (int r = 0; r < 4; ++r) STGA(r, 1, 64);
  #pragma unroll
  for (int r = 0; r < NBW; ++r) STGB(r, 1, 64);
  vm_wait<4 + NBW>();
  __builtin_amdgcn_s_barrier();
  __builtin_amdgcn_sched_barrier(0);

  for (int kt = 0; kt < NT; ++kt) {
    const int cur = kt & 1;
    const int kt2 = ((kt + 2 < NT) ? kt + 2 : NT - 1) << 6;
    const u16* As0 = &smA[cur][0];
    const u16* Bs0 = &smB[cur][0];
    short8 a[4][2], b[NBW][2];

    #pragma unroll
    for (int i = 0; i < 4; ++i) a[i][0] = *(const short8*)&As0[(((mg << 6) + (i << 4) + lr) << 6) + ch0];
    #pragma unroll
    for (int j = 0; j < NBW; ++j) b[j][0] = *(const short8*)&Bs0[((ng * (BN / 2) + (j << 4) + lr) << 6) + ch0];
    #pragma unroll
    for (int i = 0; i < 4; ++i) a[i][1] = *(const short8*)&As0[(((mg << 6) + (i << 4) + lr) << 6) + ch1];
    #pragma unroll
    for (int j = 0; j < NBW; ++j) b[j][1] = *(const short8*)&Bs0[((ng * (BN / 2) + (j << 4) + lr) << 6) + ch1];
    __builtin_amdgcn_s_setprio(1);
    #pragma unroll
    for (int i = 0; i < 4; ++i)
      #pragma unroll
      for (int j = 0; j < NBW; ++j) MFMA16(acc[i][j], a[i][0], b[j][0]);
    __builtin_amdgcn_s_setprio(0);
    asm volatile("s_waitcnt lgkmcnt(0)" ::: "memory");
    __builtin_amdgcn_s_barrier();
    __builtin_amdgcn_sched_barrier(0);

    #pragma unroll
    for (int r = 0; r < 4; ++r) STGA(r, cur, kt2);
    #pragma unroll
    for (int r = 0; r < NBW; ++r) STGB(r, cur, kt2);
    __builtin_amdgcn_sched_barrier(0);
    __builtin_amdgcn_s_setprio(1);
    #pragma unroll
    for (int i = 0; i < 4; ++i)
      #pragma unroll
      for (int j = 0; j < NBW; ++j) MFMA16(acc[i][j], a[i][1], b[j][1]);
    __builtin_amdgcn_s_setprio(0);
    vm_wait<4 + NBW>();
    __builtin_amdgcn_s_barrier();
    __builtin_amdgcn_sched_barrier(0);
  }
#undef STGA
#undef STGB

  asm volatile("s_waitcnt vmcnt(0)" ::: "memory");

  const int wrm = m0 + (mg << 6);
  const int wcn = n0 + ng * (BN / 2);
  const int lq = q << 2;
  #pragma unroll
  for (int j = 0; j < NBW; ++j) {
    const int cn = wcn + (j << 4) + lr;
    const float bv = bias[cn];
    #pragma unroll
    for (int i = 0; i < 4; ++i) {
      const int rm = wrm + (i << 4) + lq;
      #pragma unroll
      for (int rr = 0; rr < 4; ++rr) {
        float v = acc[i][j][rr] + bv;
        if constexpr (std::is_same<OutT, u16>::value) C[(size_t)(rm + rr) * N + cn] = f2bf(v);
        else                                          C[(size_t)(rm + rr) * N + cn] = v;
      }
    }
  }
}

// ---------------- Gram partials via MFMA + qsum partials ----------------
// r10: partials stored as bf16 (halves Gpart traffic 16->8 MB each way). Precision:
// G's downstream terms perturb the Taylor denominator by s1/1024 (~1e-4 rel) and
// quad/2/1024^2 (~1e-6 rel) against the constant 2048; bf16 partial rounding (2^-9)
// shifts those by ~1e-6 relative -- orders below the final bf16 G quantization.
__global__ __launch_bounds__(256)
void k_gpart2(const u16* __restrict__ QKV, u16* __restrict__ Gpart, float* __restrict__ qpart) {
  const int chunk = blockIdx.x;            // 0..15 (128 a each)
  const int nh = blockIdx.y;               // 0..63
  const int n = nh >> 4, h = nh & 15;
  const int t = threadIdx.x, w = t >> 6, lane = t & 63;
  const int lr = lane & 15, lko = (lane >> 4) << 3;

  __shared__ __align__(16) u16 Qt[64 * 136];   // x-major, a-stride 136 (17.4 KB)
  __shared__ float red[256];

  // transpose-in: thread t -> (a_local = t>>1, x-half = t&1); 4x uint4 = 64B
  const int a_local = t >> 1, xh = t & 1;
  const int a = chunk * 128 + a_local;
  const uint4* qp = (const uint4*)(QKV + (size_t)(n * 2048 + h * 128 + (a >> 4)) * 3072
                                   + ((a & 15) << 6) + (xh << 5));
  union { u16 s[8]; uint4 v; } qv[4];
  #pragma unroll
  for (int j = 0; j < 4; ++j) qv[j].v = qp[j];
  #pragma unroll
  for (int j = 0; j < 4; ++j)
    #pragma unroll
    for (int e = 0; e < 8; ++e)
      Qt[((xh << 5) + j * 8 + e) * 136 + a_local] = qv[j].s[e];   // <=2-way bank alias (free)
  __syncthreads();

  // qsum partial: thread (x = t&63, c = t>>6) sums Qt[x][c*32 .. +31]
  {
    const int x = t & 63, c = t >> 6;
    const u16* base = &Qt[x * 136 + (c << 5)];
    float s = 0.f;
    #pragma unroll
    for (int k = 0; k < 4; ++k) {
      float f[8]; unpack8(*(const uint4*)(base + k * 8), f);
      #pragma unroll
      for (int e = 0; e < 8; ++e) s += f[e];
    }
    red[t] = s;
  }
  __syncthreads();
  if (t < 64)
    qpart[((size_t)nh * 16 + chunk) * 64 + t] = red[t] + red[t + 64] + red[t + 128] + red[t + 192];

  // Gram: K-loop over 128 a in 4 steps of 32; wave w owns C row-block i=w
  floatx4 acc[4];
  #pragma unroll
  for (int j = 0; j < 4; ++j)
    #pragma unroll
    for (int k = 0; k < 4; ++k) acc[j][k] = 0.f;
  #pragma unroll
  for (int ks = 0; ks < 4; ++ks) {
    short8 f[4];
    #pragma unroll
    for (int i = 0; i < 4; ++i) f[i] = *(const short8*)&Qt[((i << 4) + lr) * 136 + (ks << 5) + lko];
    #pragma unroll
    for (int j = 0; j < 4; ++j)
      acc[j] = __builtin_amdgcn_mfma_f32_16x16x32_bf16(f[w], f[j], acc[j], 0, 0, 0);
  }
  u16* o = Gpart + ((size_t)nh * 16 + chunk) * 4096;
  const int quad = lane >> 4;
  #pragma unroll
  for (int j = 0; j < 4; ++j)
    #pragma unroll
    for (int r = 0; r < 4; ++r)
      o[((w << 4) + (quad << 2) + r) * 64 + (j << 4) + lr] = f2bf(acc[j][r]);
}

// ---------------- Gpart/qpart reduce -> bf16 G + fp32 qs (bf16 partials in) ----------------
__global__ __launch_bounds__(256)
void k_gred(const u16* __restrict__ Gpart, const float* __restrict__ qpart,
            u16* __restrict__ G, float* __restrict__ qs_g) {
  const int nh = blockIdx.y;               // 0..63
  const int t = threadIdx.x;
  const int e0 = (blockIdx.x << 9) + (t << 1);   // 2 elems/thread, 512/block
  const u16* gp = Gpart + (size_t)nh * 65536 + e0;
  float sx = 0.f, sy = 0.f;
  #pragma unroll
  for (int c = 0; c < 16; ++c) {
    unsigned v = *(const unsigned*)(gp + c * 4096);
    sx += bf2f((u16)(v & 0xffffu));
    sy += bf2f((u16)(v >> 16));
  }
  *(unsigned*)(G + (size_t)nh * 4096 + e0) = (unsigned)f2bf(sx) | ((unsigned)f2bf(sy) << 16);
  if (blockIdx.x == 0 && t < 64) {
    float s = 0.f;
    #pragma unroll
    for (int rc = 0; rc < 16; ++rc) s += qpart[((size_t)nh * 16 + rc) * 64 + t];
    qs_g[nh * 64 + t] = s;
  }
}

// ---------------- fused: load G -> U = K*G (MFMA, LDS) -> Taylor denom/diag -> mid = diag*V ----
// r8 form (verified): grid 16x64 (4 blocks/CU), 128 a-rows/block, LDS 26.7 KB.
__global__ __launch_bounds__(256)
void k_kgd(const u16* __restrict__ QKV, const u16* __restrict__ G,
           const float* __restrict__ qs_g, u16* __restrict__ mid) {
  const int chunk = blockIdx.x;            // 0..15 (128 a each)
  const int nh = blockIdx.y;               // 0..63
  const int n = nh >> 4, h = nh & 15;
  const int t = threadIdx.x, w = t >> 6, lane = t & 63;
  const int lr = lane & 15, lko = (lane >> 4) << 3;

  __shared__ __align__(16) u16 Gs[4096];      // bf16 G_h, 64x64 (8 KB)
  __shared__ __align__(16) u16 Us[128 * 72];  // bf16 U rows, padded stride 72 (18.4 KB)
  __shared__ float qs[64];

  // --- stage 0: coalesced copy of pre-reduced G (8 KB) + qs ---
  const uint4* gsrc = (const uint4*)(G + (size_t)nh * 4096);
  ((uint4*)Gs)[t] = gsrc[t];
  ((uint4*)Gs)[256 + t] = gsrc[256 + t];
  if (t < 64) qs[t] = qs_g[nh * 64 + t];
  __syncthreads();

  // --- stage 1: U = K * G via MFMA (each wave: 32 a-rows x 64 cols) ---
  short8 af[2][2], bfr[4][2];
  #pragma unroll
  for (int i = 0; i < 2; ++i) {
    const int arow = chunk * 8 + (w << 1) + i;          // (a>>4) within head
    const u16* kp = QKV + (size_t)(n * 2048 + h * 128 + arow) * 3072 + 1024 + lr * 64;
    #pragma unroll
    for (int s = 0; s < 2; ++s) af[i][s] = *(const short8*)(kp + s * 32 + lko);
  }
  #pragma unroll
  for (int j = 0; j < 4; ++j)
    #pragma unroll
    for (int s = 0; s < 2; ++s)
      bfr[j][s] = *(const short8*)&Gs[((j << 4) + lr) * 64 + s * 32 + lko];
  floatx4 acc[2][4];
  #pragma unroll
  for (int i = 0; i < 2; ++i)
    #pragma unroll
    for (int j = 0; j < 4; ++j)
      #pragma unroll
      for (int k = 0; k < 4; ++k) acc[i][j][k] = 0.f;
  #pragma unroll
  for (int s = 0; s < 2; ++s)
    #pragma unroll
    for (int i = 0; i < 2; ++i)
      #pragma unroll
      for (int j = 0; j < 4; ++j)
        acc[i][j] = __builtin_amdgcn_mfma_f32_16x16x32_bf16(af[i][s], bfr[j][s], acc[i][j], 0, 0, 0);
  const int rq = (lane >> 4) << 2;
  #pragma unroll
  for (int i = 0; i < 2; ++i)
    #pragma unroll
    for (int j = 0; j < 4; ++j)
      #pragma unroll
      for (int r = 0; r < 4; ++r) {
        int a_local = (w << 5) + (i << 4) + rq + r;     // 0..127
        Us[a_local * 72 + (j << 4) + lr] = f2bf(acc[i][j][r]);
      }
  __syncthreads();

  // --- stage 2: 2 threads per a (32 x's each): Taylor denom + diag; mid = diag * V ---
  const int al = t >> 1, xh = t & 1;
  const int b = chunk * 128 + al;          // a within head
  const int R = n * 2048 + h * 128 + (b >> 4);
  const u16* row = QKV + (size_t)R * 3072 + ((b & 15) << 6) + (xh << 5);
  const uint4* qp = (const uint4*)row;
  const uint4* kp = (const uint4*)(row + 1024);
  const uint4* vp = (const uint4*)(row + 2048);
  const uint4* up = (const uint4*)&Us[al * 72 + (xh << 5)];
  float sbb = 0.f, s1 = 0.f, quad = 0.f;
  #pragma unroll
  for (int xo = 0; xo < 4; ++xo) {
    float kx[8], qx[8], ux[8];
    unpack8(kp[xo], kx); unpack8(qp[xo], qx); unpack8(up[xo], ux);
    #pragma unroll
    for (int xi = 0; xi < 8; ++xi) {
      sbb  += qx[xi] * kx[xi];
      quad += ux[xi] * kx[xi];
      s1   += qs[(xh << 5) + xo * 8 + xi] * kx[xi];
    }
  }
  sbb  += __shfl_xor(sbb, 1);              // pair-combine (lanes 2k <-> 2k+1)
  quad += __shfl_xor(quad, 1);
  s1   += __shfl_xor(s1, 1);
  const float c1 = 0.0009765625f;  // 1/1024
  float denom = 2048.f + s1 * c1 + 0.5f * quad * c1 * c1;
  float d = expf(sbb * c1) / denom;
  u16* mp = mid + (size_t)R * 1024 + ((b & 15) << 6) + (xh << 5);
  #pragma unroll
  for (int xo = 0; xo < 4; ++xo) {
    float f[8]; unpack8(vp[xo], f);
    union { u16 s[8]; uint4 v; } o;
    #pragma unroll
    for (int k = 0; k < 8; ++k) o.s[k] = f2bf(f[k] * d);
    *(uint4*)(mp + xo * 8) = o.v;
  }
}

// ---------------- launch ----------------
extern "C" void kernel_launch(void* const* d_in, const int* in_sizes, int n_in,
                              void* d_out, int out_size, void* d_ws, size_t ws_size,
                              hipStream_t stream) {
  (void)in_sizes; (void)n_in; (void)out_size; (void)ws_size;
  const float* X  = (const float*)d_in[0];
  const float* Wq = (const float*)d_in[1];
  const float* bq = (const float*)d_in[2];
  const float* Wk = (const float*)d_in[3];
  const float* bk = (const float*)d_in[4];
  const float* Wv = (const float*)d_in[5];
  const float* bv = (const float*)d_in[6];
  const float* Wo = (const float*)d_in[7];
  const float* bo = (const float*)d_in[8];
  float* out = (float*)d_out;
  char* ws = (char*)d_ws;

  // ws+0 (16 MB) triple use, strictly stream-ordered:
  //   Xb (prep->QKV GEMM)  ->  Gpart bf16 64x16x4096 = 8 MB (gpart2->gred)  ->  mid (kgd->outproj)
  u16*   Xb    = (u16*)(ws + 0);
  u16*   Gpart = (u16*)(ws + 0);
  u16*   mid   = (u16*)(ws + 0);
  u16*   Wqkvt = (u16*)(ws + 16777216);          //  6 MB (dead after QKV GEMM)
  u16*   Gred  = (u16*)(ws + 16777216);          // 512 KB, overlays dead Wqkvt
  float* qsg   = (float*)(ws + 17301504);        //  16 KB, overlays dead Wqkvt
  u16*   Wot   = (u16*)(ws + 23068672);          //  2 MB
  float* bias3 = (float*)(ws + 25165824);        // 12 KB
  u16*   QKV   = (u16*)(ws + 25182208);          // 48 MB (8192 x [Q|K|V])
  float* qpart = (float*)(ws + 75513856);        // 256 KB

  k_prep<<<8192, 256, 0, stream>>>(X, Wq, Wk, Wv, Wo, bq, bk, bv, Xb, Wqkvt, Wot, bias3);
  // QKV GEMM: measured-best r4 kernel, grid 512 = exactly 2 rounds
  k_gemm_192<u16><<<512, 512, 0, stream>>>(Xb, Wqkvt, bias3, QKV, 8192, 3072, 1024);
  // Gram partials: 16 chunks x 64 nh = 1024 blocks (4/CU), bf16 partials
  k_gpart2<<<dim3(16, 64), 256, 0, stream>>>(QKV, Gpart, qpart);
  k_gred<<<dim3(8, 64), 256, 0, stream>>>(Gpart, qpart, Gred, qsg);
  // kgd: 16 chunks x 64 nh = 1024 blocks (4/CU)
  k_kgd<<<dim3(16, 64), 256, 0, stream>>>(QKV, Gred, qsg, mid);
  // out-projection: 128x128 tiles, 2 blocks/CU -> grid 512 (r8-best config)
  k_gemm_a<128, float><<<512, 256, 0, stream>>>(mid, Wot, bo, out, 8192, 1024, 1024);
}